// Round 17
// baseline (156.758 us; speedup 1.0000x reference)
//
#include <hip/hip_runtime.h>
#include <stdint.h>

// QuantizedLinear: out[M,N] = (x[M,K] @ Wq^T) * scale[N] + bias[N]
// M = B*S = 4096, K = IN = 4096, N = OUT = 4096.
// Round 17: faithful m201-template port. 256x256 tile, BK=64, 8 waves
// (2Mx4N, each 128x64). 2 LDS buffers x 64KB = 128KB. Per K-tile: 4
// quadrant-phases {ds_read subtile || 1 half-tile stage (2 gld16) ->
// barrier -> lgkmcnt(0) -> 16 MFMA -> barrier}; register reuse across
// quadrants (reads/phase = 12/4/8/0); ONE vmcnt(4) per K-tile at the q3
// boundary (in-order retirement certifies next tile landed; 2 half-tiles
// stay in flight). Pre-tiled f16 planes keep all LDS reads conflict-free.

#define M_DIM 4096
#define N_DIM 4096
#define K_DIM 4096
#define KT_N 64            // K / 64
#define TILE_SH 16384      // one 256x64 f16 operand tile in shorts (32 KB)
#define HALF_SH 8192       // half-tile (128 rows x 64 k) in shorts (16 KB)
#define BUF_SH 32768       // A tile + B tile per buffer (64 KB)
#define BSEC 16384         // B section offset within a buffer (shorts)

typedef _Float16 f16x8 __attribute__((ext_vector_type(8)));
typedef __bf16   bf16x8v __attribute__((ext_vector_type(8)));
typedef float    f32x4 __attribute__((ext_vector_type(4)));

__device__ __forceinline__ unsigned short f32_f16_bits(float f) {
    _Float16 h = (_Float16)f;
    return __builtin_bit_cast(unsigned short, h);
}

__device__ __forceinline__ void gld16(const unsigned short* g, unsigned short* l) {
    __builtin_amdgcn_global_load_lds(
        (const __attribute__((address_space(1))) unsigned int*)g,
        (__attribute__((address_space(3))) unsigned int*)l,
        16, 0, 0);
}

// ---------- pre-pass: x (f32) -> f16 plane, BK=64 TILED layout ----------
// AT: [mi(16)][kt(64)] tiles of [half(2)][ks(8)][r(128)][8] (exact LDS image)
__global__ __launch_bounds__(256) void cvt_x_f16(const float* __restrict__ x,
                                                 unsigned short* __restrict__ AT) {
    const int b  = blockIdx.x;        // 16 * 64 = 1024
    const int mi = b >> 6;
    const int kt = b & 63;
    const int r  = threadIdx.x;       // 0..255

    const float* xp = x + (size_t)(mi * 256 + r) * K_DIM + kt * 64;
    unsigned short hh[64];
    #pragma unroll
    for (int j4 = 0; j4 < 16; ++j4) {
        float4 v = *(const float4*)(xp + j4 * 4);
        hh[j4*4+0] = f32_f16_bits(v.x);
        hh[j4*4+1] = f32_f16_bits(v.y);
        hh[j4*4+2] = f32_f16_bits(v.z);
        hh[j4*4+3] = f32_f16_bits(v.w);
    }
    unsigned short* o = AT + (size_t)(mi * KT_N + kt) * TILE_SH
                      + (r >> 7) * HALF_SH + (r & 127) * 8;
    #pragma unroll
    for (int ks = 0; ks < 8; ++ks) {
        uint4 p;
        p.x = (unsigned)hh[ks*8+0] | ((unsigned)hh[ks*8+1] << 16);
        p.y = (unsigned)hh[ks*8+2] | ((unsigned)hh[ks*8+3] << 16);
        p.z = (unsigned)hh[ks*8+4] | ((unsigned)hh[ks*8+5] << 16);
        p.w = (unsigned)hh[ks*8+6] | ((unsigned)hh[ks*8+7] << 16);
        *(uint4*)(o + ks * 1024) = p;     // (ks*128 + r&127)*8
    }
}

// ---------- pre-pass: Wq (int) -> f16 plane (exact), BK=64 TILED layout ----------
// BT: [ni(16)][kt(64)] tiles of [half(2)][ks(8)][c(128)][8]
__global__ __launch_bounds__(256) void cvt_w_f16(const int* __restrict__ wq,
                                                 unsigned short* __restrict__ BT) {
    const int b  = blockIdx.x;        // 16 * 64 = 1024
    const int ni = b >> 6;
    const int kt = b & 63;
    const int c  = threadIdx.x;       // 0..255

    const int* wp = wq + (size_t)(ni * 256 + c) * K_DIM + kt * 64;
    unsigned short bb[64];
    #pragma unroll
    for (int j4 = 0; j4 < 16; ++j4) {
        int4 v = *(const int4*)(wp + j4 * 4);
        bb[j4*4+0] = f32_f16_bits((float)v.x);
        bb[j4*4+1] = f32_f16_bits((float)v.y);
        bb[j4*4+2] = f32_f16_bits((float)v.z);
        bb[j4*4+3] = f32_f16_bits((float)v.w);
    }
    unsigned short* ob = BT + (size_t)(ni * KT_N + kt) * TILE_SH
                       + (c >> 7) * HALF_SH + (c & 127) * 8;
    #pragma unroll
    for (int ks = 0; ks < 8; ++ks) {
        uint4 p;
        p.x = (unsigned)bb[ks*8+0] | ((unsigned)bb[ks*8+1] << 16);
        p.y = (unsigned)bb[ks*8+2] | ((unsigned)bb[ks*8+3] << 16);
        p.z = (unsigned)bb[ks*8+4] | ((unsigned)bb[ks*8+5] << 16);
        p.w = (unsigned)bb[ks*8+6] | ((unsigned)bb[ks*8+7] << 16);
        *(uint4*)(ob + ks * 1024) = p;
    }
}

// ---------- GEMM: 256x256, BK=64, 8 waves, 4 quadrant-phases per K-tile ----------
__global__ __launch_bounds__(512, 1) void gemm_pipe(
    const unsigned short* __restrict__ AT,
    const unsigned short* __restrict__ BT,
    const float* __restrict__ scale, const float* __restrict__ bias,
    float* __restrict__ out)
{
    __shared__ unsigned short lds[2 * BUF_SH];   // 128 KB

    const int t    = threadIdx.x;     // 0..511
    const int lane = t & 63;
    const int wid  = t >> 6;          // 0..7
    const int wr   = wid >> 2;        // 0..1  (128-row slab -> A half = wr)
    const int wc   = wid & 3;         // 0..3  (64-col slab -> B half = wc>>1)
    const int lr   = lane & 15;
    const int ksf  = lane >> 4;

    // XCD swizzle: 256 blocks, 256 % 8 == 0 -> bijective
    const int bid = blockIdx.x;
    const int swz = (bid & 7) * 32 + (bid >> 3);
    const int mi  = swz & 15;
    const int ni  = swz >> 4;

    // staging: half-tile = 1024 x 16B chunks; thread t owns chunks t, t+512
    const int lbA = (t & ~63) * 8;    // wave-uniform chunk base (shorts)
    const unsigned short* gA = AT + (size_t)mi * KT_N * TILE_SH + t * 8;
    const unsigned short* gB = BT + (size_t)ni * KT_N * TILE_SH + t * 8;

    // stage half h of tile `tile` (A: sec=0/src=gA, B: sec=BSEC/src=gB)
#define STG(bufb, sec, h, src, tile) do {                                     \
    gld16((src) + (size_t)(tile) * TILE_SH + (h) * HALF_SH,                   \
          lds + (bufb) + (sec) + (h) * HALF_SH + lbA);                        \
    gld16((src) + (size_t)(tile) * TILE_SH + (h) * HALF_SH + 4096,            \
          lds + (bufb) + (sec) + (h) * HALF_SH + lbA + 4096);                 \
} while (0)

    // fragment bases (shorts); frag offsets add m*128 / n*128 and kk*4096
    const int baseA = wr * HALF_SH + ksf * 1024 + lr * 8;
    const int baseB = BSEC + (wc >> 1) * HALF_SH + ksf * 1024
                    + ((wc & 1) * 64 + lr) * 8;

    f32x4 acc[8][4];
    #pragma unroll
    for (int m = 0; m < 8; ++m)
        #pragma unroll
        for (int n = 0; n < 4; ++n)
            acc[m][n] = (f32x4){0.f, 0.f, 0.f, 0.f};

    f16x8 a0[8], a1[8], bq[8];   // a: [m][kk] flat m*2+kk; b: [n][kk] flat

    // prologue: tile0 fully -> buf0; tile1 B-h0,A-h0 -> buf1.
    // vmcnt(4): tile 0 (first 8 loads) landed; tile1's 2 halves in flight.
    STG(0,      BSEC, 0, gB, 0);
    STG(0,      0,    0, gA, 0);
    STG(0,      BSEC, 1, gB, 0);
    STG(0,      0,    1, gA, 0);
    STG(BUF_SH, BSEC, 0, gB, 1);
    STG(BUF_SH, 0,    0, gA, 1);
    asm volatile("s_waitcnt vmcnt(4)" ::: "memory");
    __builtin_amdgcn_s_barrier();

    for (int kt = 0; kt < KT_N; ++kt) {
        const int curB = (kt & 1) * BUF_SH;
        const int othB = BUF_SH - curB;
        const unsigned short* Lb = lds + curB;

        // ---- q0 (m0-3 x n0-1): 12 ds_read; stage B-h1(kt+1) -> othB ----
        #pragma unroll
        for (int n = 0; n < 2; ++n)
            #pragma unroll
            for (int kk = 0; kk < 2; ++kk)
                bq[n*2+kk] = *(const f16x8*)(Lb + baseB + n*128 + kk*4096);
        #pragma unroll
        for (int m = 0; m < 4; ++m)
            #pragma unroll
            for (int kk = 0; kk < 2; ++kk)
                a0[m*2+kk] = *(const f16x8*)(Lb + baseA + m*128 + kk*4096);
        if (kt + 1 < KT_N) STG(othB, BSEC, 1, gB, kt + 1);
        __builtin_amdgcn_s_barrier();
        asm volatile("s_waitcnt lgkmcnt(0)" ::: "memory");
        __builtin_amdgcn_sched_barrier(0);
        __builtin_amdgcn_s_setprio(1);
        #pragma unroll
        for (int m = 0; m < 4; ++m)
            #pragma unroll
            for (int n = 0; n < 2; ++n)
                #pragma unroll
                for (int kk = 0; kk < 2; ++kk)
                    acc[m][n] = __builtin_amdgcn_mfma_f32_16x16x32_f16(
                        a0[m*2+kk], bq[n*2+kk], acc[m][n], 0, 0, 0);
        __builtin_amdgcn_s_setprio(0);
        __builtin_amdgcn_s_barrier();

        // ---- q1 (m0-3 x n2-3): 4 ds_read; stage A-h1(kt+1) -> othB ----
        #pragma unroll
        for (int n = 2; n < 4; ++n)
            #pragma unroll
            for (int kk = 0; kk < 2; ++kk)
                bq[n*2+kk] = *(const f16x8*)(Lb + baseB + n*128 + kk*4096);
        if (kt + 1 < KT_N) STG(othB, 0, 1, gA, kt + 1);
        __builtin_amdgcn_s_barrier();
        asm volatile("s_waitcnt lgkmcnt(0)" ::: "memory");
        __builtin_amdgcn_sched_barrier(0);
        __builtin_amdgcn_s_setprio(1);
        #pragma unroll
        for (int m = 0; m < 4; ++m)
            #pragma unroll
            for (int n = 2; n < 4; ++n)
                #pragma unroll
                for (int kk = 0; kk < 2; ++kk)
                    acc[m][n] = __builtin_amdgcn_mfma_f32_16x16x32_f16(
                        a0[m*2+kk], bq[n*2+kk], acc[m][n], 0, 0, 0);
        __builtin_amdgcn_s_setprio(0);
        __builtin_amdgcn_s_barrier();

        // ---- q2 (m4-7 x n0-1): 8 ds_read; stage B-h0(kt+2) -> curB ----
        #pragma unroll
        for (int m = 0; m < 4; ++m)
            #pragma unroll
            for (int kk = 0; kk < 2; ++kk)
                a1[m*2+kk] = *(const f16x8*)(Lb + baseA + (m+4)*128 + kk*4096);
        if (kt + 2 < KT_N) STG(curB, BSEC, 0, gB, kt + 2);
        __builtin_amdgcn_s_barrier();
        asm volatile("s_waitcnt lgkmcnt(0)" ::: "memory");
        __builtin_amdgcn_sched_barrier(0);
        __builtin_amdgcn_s_setprio(1);
        #pragma unroll
        for (int m = 4; m < 8; ++m)
            #pragma unroll
            for (int n = 0; n < 2; ++n)
                #pragma unroll
                for (int kk = 0; kk < 2; ++kk)
                    acc[m][n] = __builtin_amdgcn_mfma_f32_16x16x32_f16(
                        a1[(m-4)*2+kk], bq[n*2+kk], acc[m][n], 0, 0, 0);
        __builtin_amdgcn_s_setprio(0);
        __builtin_amdgcn_s_barrier();

        // ---- q3 (m4-7 x n2-3): 0 ds_read; stage A-h0(kt+2) -> curB ----
        if (kt + 2 < KT_N) STG(curB, 0, 0, gA, kt + 2);
        __builtin_amdgcn_s_barrier();
        __builtin_amdgcn_s_setprio(1);
        #pragma unroll
        for (int m = 4; m < 8; ++m)
            #pragma unroll
            for (int n = 2; n < 4; ++n)
                #pragma unroll
                for (int kk = 0; kk < 2; ++kk)
                    acc[m][n] = __builtin_amdgcn_mfma_f32_16x16x32_f16(
                        a1[(m-4)*2+kk], bq[n*2+kk], acc[m][n], 0, 0, 0);
        __builtin_amdgcn_s_setprio(0);
        // tile boundary: certify tile kt+1 (its last load A-h1 was issued at
        // this tile's q1; only the 2 half-tiles staged at q2/q3 follow it).
        if (kt + 2 < KT_N) asm volatile("s_waitcnt vmcnt(4)" ::: "memory");
        else               asm volatile("s_waitcnt vmcnt(0)" ::: "memory");
        __builtin_amdgcn_s_barrier();
    }
#undef STG

    // epilogue: C/D layout col=lane&15, row=(lane>>4)*4+j (m89-verified)
    #pragma unroll
    for (int n = 0; n < 4; ++n) {
        const int col = ni * 256 + wc * 64 + n * 16 + lr;
        const float sc = scale[col];
        const float bi = bias[col];
        #pragma unroll
        for (int m = 0; m < 8; ++m) {
            const int r0 = mi * 256 + wr * 128 + m * 16 + ksf * 4;
            #pragma unroll
            for (int j = 0; j < 4; ++j)
                out[(size_t)(r0 + j) * N_DIM + col] = acc[m][n][j] * sc + bi;
        }
    }
}

// ---------- fallback (ws too small): reg-staged 2-plane bf16, proven structure ----------
__device__ __forceinline__ unsigned short f32_bf16_rne(float f) {
    unsigned u = __float_as_uint(f);
    u += 0x7FFFu + ((u >> 16) & 1u);
    return (unsigned short)(u >> 16);
}

__device__ __forceinline__ void cvt2(float a, float b, unsigned& hi2, unsigned& lo2) {
    unsigned short ha = f32_bf16_rne(a), hb = f32_bf16_rne(b);
    float fa = __uint_as_float((unsigned)ha << 16);
    float fb = __uint_as_float((unsigned)hb << 16);
    unsigned short la = f32_bf16_rne(a - fa), lb = f32_bf16_rne(b - fb);
    hi2 = (unsigned)ha | ((unsigned)hb << 16);
    lo2 = (unsigned)la | ((unsigned)lb << 16);
}

__global__ __launch_bounds__(256) void gemm_fb(
    const float* __restrict__ X, const int* __restrict__ Wq,
    const float* __restrict__ scale, const float* __restrict__ bias,
    float* __restrict__ out)
{
    __shared__ unsigned short sAh[4 * 128 * 8];
    __shared__ unsigned short sAl[4 * 128 * 8];
    __shared__ unsigned short sB [4 * 128 * 8];

    const int t    = threadIdx.x;
    const int lane = t & 63;
    const int wid  = t >> 6;
    const int brow = blockIdx.y * 128;
    const int bcol = blockIdx.x * 128;

    const int c1 = t,        c2 = t + 256;
    const int r1 = c1 & 127, s1 = c1 >> 7;
    const int r2 = c2 & 127, s2 = c2 >> 7;

    const int wr  = wid >> 1, wc = wid & 1;
    const int lr  = lane & 15;
    const int ksf = lane >> 4;

    f32x4 acc[4][4];
    #pragma unroll
    for (int m = 0; m < 4; ++m)
        #pragma unroll
        for (int n = 0; n < 4; ++n)
            acc[m][n] = (f32x4){0.f, 0.f, 0.f, 0.f};

    for (int k0 = 0; k0 < K_DIM; k0 += 32) {
        #pragma unroll
        for (int cc = 0; cc < 2; ++cc) {
            const int c = cc ? c2 : c1;
            const int r = cc ? r2 : r1;
            const int s = cc ? s2 : s1;
            const float* xa = X + (size_t)(brow + r) * K_DIM + k0 + s * 8;
            float4 v0 = *(const float4*)(xa);
            float4 v1 = *(const float4*)(xa + 4);
            uint4 hv, lv;
            cvt2(v0.x, v0.y, hv.x, lv.x);
            cvt2(v0.z, v0.w, hv.y, lv.y);
            cvt2(v1.x, v1.y, hv.z, lv.z);
            cvt2(v1.z, v1.w, hv.w, lv.w);
            *(uint4*)(sAh + c * 8) = hv;
            *(uint4*)(sAl + c * 8) = lv;

            const int* wa = Wq + (size_t)(bcol + r) * K_DIM + k0 + s * 8;
            int4 w0 = *(const int4*)(wa);
            int4 w1 = *(const int4*)(wa + 4);
            uint4 wv;
            wv.x = (unsigned)f32_bf16_rne((float)w0.x) | ((unsigned)f32_bf16_rne((float)w0.y) << 16);
            wv.y = (unsigned)f32_bf16_rne((float)w0.z) | ((unsigned)f32_bf16_rne((float)w0.w) << 16);
            wv.z = (unsigned)f32_bf16_rne((float)w1.x) | ((unsigned)f32_bf16_rne((float)w1.y) << 16);
            wv.w = (unsigned)f32_bf16_rne((float)w1.z) | ((unsigned)f32_bf16_rne((float)w1.w) << 16);
            *(uint4*)(sB + c * 8) = wv;
        }
        __syncthreads();

        bf16x8v ah[4], al[4], bb[4];
        #pragma unroll
        for (int m = 0; m < 4; ++m) {
            const int row = wr * 64 + m * 16 + lr;
            ah[m] = *(const bf16x8v*)(sAh + (ksf * 128 + row) * 8);
            al[m] = *(const bf16x8v*)(sAl + (ksf * 128 + row) * 8);
        }
        #pragma unroll
        for (int n = 0; n < 4; ++n) {
            const int row = wc * 64 + n * 16 + lr;
            bb[n] = *(const bf16x8v*)(sB + (ksf * 128 + row) * 8);
        }

        #pragma unroll
        for (int m = 0; m < 4; ++m)
            #pragma unroll
            for (int n = 0; n < 4; ++n) {
                acc[m][n] = __builtin_amdgcn_mfma_f32_16x16x32_bf16(ah[m], bb[n], acc[m][n], 0, 0, 0);
                acc[m][n] = __builtin_amdgcn_mfma_f32_16x16x32_bf16(al[m], bb[n], acc[m][n], 0, 0, 0);
            }
        __syncthreads();
    }

    #pragma unroll
    for (int n = 0; n < 4; ++n) {
        const int col = bcol + wc * 64 + n * 16 + lr;
        const float sc = scale[col];
        const float bi = bias[col];
        #pragma unroll
        for (int m = 0; m < 4; ++m) {
            const int r0 = brow + wr * 64 + m * 16 + ksf * 4;
            #pragma unroll
            for (int j = 0; j < 4; ++j)
                out[(size_t)(r0 + j) * N_DIM + col] = acc[m][n][j] * sc + bi;
        }
    }
}

extern "C" void kernel_launch(void* const* d_in, const int* in_sizes, int n_in,
                              void* d_out, int out_size, void* d_ws, size_t ws_size,
                              hipStream_t stream) {
    const float* x     = (const float*)d_in[0];
    const int*   wq    = (const int*)d_in[1];
    const float* scale = (const float*)d_in[2];
    const float* bias  = (const float*)d_in[3];
    float*       out   = (float*)d_out;

    const size_t planeElems = (size_t)M_DIM * K_DIM;        // 16,777,216
    const size_t planeBytes = planeElems * sizeof(unsigned short);  // 32 MiB

    if (ws_size >= 2 * planeBytes) {
        unsigned short* AT = (unsigned short*)d_ws;
        unsigned short* BT = AT + planeElems;
        cvt_x_f16<<<1024, 256, 0, stream>>>(x, AT);
        cvt_w_f16<<<1024, 256, 0, stream>>>(wq, BT);
        gemm_pipe<<<256, 512, 0, stream>>>(AT, BT, scale, bias, out);
    } else {
        dim3 grid(N_DIM / 128, M_DIM / 128);
        gemm_fb<<<grid, 256, 0, stream>>>(x, wq, scale, bias, out);
    }
}